// Round 1
// baseline (1463.383 us; speedup 1.0000x reference)
//
#include <hip/hip_runtime.h>
#include <cstddef>
#include <cstdint>

#define NB 4
#define S_LEN 2048
#define DK 1024  // D_IN == D_OUT == 1024

// ---------------------------------------------------------------------------
// K1: fused QKV projection.  C_z[m][n] = sum_k X[m][k]*W_z[n][k] + b_z[n]
// M = B*S = 8192, N = 1024, K = 1024.  grid(M/64, N/64, 3), block(16,16).
// LDS tiles stored k-major [16][68] (pad 68 keeps float4 alignment, ~2-way
// bank conflicts only, which are free on CDNA4).
// ---------------------------------------------------------------------------
__global__ __launch_bounds__(256) void qkv_gemm(
    const float* __restrict__ x,
    const float* __restrict__ Wq, const float* __restrict__ bq,
    const float* __restrict__ Wk, const float* __restrict__ bk,
    const float* __restrict__ Wv, const float* __restrict__ bv,
    float* __restrict__ q, float* __restrict__ k, float* __restrict__ v)
{
    const float* W; const float* bias; float* out;
    if (blockIdx.z == 0)      { W = Wq; bias = bq; out = q; }
    else if (blockIdx.z == 1) { W = Wk; bias = bk; out = k; }
    else                      { W = Wv; bias = bv; out = v; }

    __shared__ float As[16][68];
    __shared__ float Bs[16][68];
    const int tx = threadIdx.x, ty = threadIdx.y;
    const int tid = ty * 16 + tx;
    const int m0 = blockIdx.x * 64, n0 = blockIdx.y * 64;
    const int lrow = tid >> 2;        // 0..63
    const int lq   = (tid & 3) * 4;   // 0,4,8,12

    float acc[4][4] = {};

    for (int k0 = 0; k0 < DK; k0 += 16) {
        float4 a4 = *(const float4*)&x[(size_t)(m0 + lrow) * DK + k0 + lq];
        float4 b4 = *(const float4*)&W[(size_t)(n0 + lrow) * DK + k0 + lq];
        As[lq+0][lrow] = a4.x; As[lq+1][lrow] = a4.y; As[lq+2][lrow] = a4.z; As[lq+3][lrow] = a4.w;
        Bs[lq+0][lrow] = b4.x; Bs[lq+1][lrow] = b4.y; Bs[lq+2][lrow] = b4.z; Bs[lq+3][lrow] = b4.w;
        __syncthreads();
        #pragma unroll
        for (int kk = 0; kk < 16; ++kk) {
            float4 a = *(const float4*)&As[kk][ty * 4];
            float4 b = *(const float4*)&Bs[kk][tx * 4];
            float av[4] = {a.x, a.y, a.z, a.w};
            float bw[4] = {b.x, b.y, b.z, b.w};
            #pragma unroll
            for (int r = 0; r < 4; ++r)
                #pragma unroll
                for (int c = 0; c < 4; ++c)
                    acc[r][c] += av[r] * bw[c];
        }
        __syncthreads();
    }
    #pragma unroll
    for (int r = 0; r < 4; ++r) {
        #pragma unroll
        for (int c = 0; c < 4; ++c) {
            int m = m0 + ty * 4 + r, n = n0 + tx * 4 + c;
            out[(size_t)m * DK + n] = acc[r][c] + bias[n];
        }
    }
}

// ---------------------------------------------------------------------------
// K2: scores.  P[b][i][j] = (q[b,i,:]·k[b,j,:]) / 32.
// grid(S/64, S/64, B); tiles with bj > bi are entirely causal-masked -> skip.
// ---------------------------------------------------------------------------
__global__ __launch_bounds__(256) void score_gemm(
    const float* __restrict__ q, const float* __restrict__ k,
    float* __restrict__ P)
{
    const int bi = blockIdx.x, bj = blockIdx.y, b = blockIdx.z;
    if (bj > bi) return;  // whole tile above diagonal

    const float* A  = q + (size_t)b * S_LEN * DK;
    const float* Bm = k + (size_t)b * S_LEN * DK;
    float* Pb = P + (size_t)b * S_LEN * S_LEN;

    __shared__ float As[16][68];
    __shared__ float Bs[16][68];
    const int tx = threadIdx.x, ty = threadIdx.y;
    const int tid = ty * 16 + tx;
    const int m0 = bi * 64, n0 = bj * 64;
    const int lrow = tid >> 2;
    const int lq   = (tid & 3) * 4;

    float acc[4][4] = {};

    for (int k0 = 0; k0 < DK; k0 += 16) {
        float4 a4 = *(const float4*)&A [(size_t)(m0 + lrow) * DK + k0 + lq];
        float4 b4 = *(const float4*)&Bm[(size_t)(n0 + lrow) * DK + k0 + lq];
        As[lq+0][lrow] = a4.x; As[lq+1][lrow] = a4.y; As[lq+2][lrow] = a4.z; As[lq+3][lrow] = a4.w;
        Bs[lq+0][lrow] = b4.x; Bs[lq+1][lrow] = b4.y; Bs[lq+2][lrow] = b4.z; Bs[lq+3][lrow] = b4.w;
        __syncthreads();
        #pragma unroll
        for (int kk = 0; kk < 16; ++kk) {
            float4 a = *(const float4*)&As[kk][ty * 4];
            float4 b = *(const float4*)&Bs[kk][tx * 4];
            float av[4] = {a.x, a.y, a.z, a.w};
            float bw[4] = {b.x, b.y, b.z, b.w};
            #pragma unroll
            for (int r = 0; r < 4; ++r)
                #pragma unroll
                for (int c = 0; c < 4; ++c)
                    acc[r][c] += av[r] * bw[c];
        }
        __syncthreads();
    }
    #pragma unroll
    for (int r = 0; r < 4; ++r)
        #pragma unroll
        for (int c = 0; c < 4; ++c)
            Pb[(size_t)(m0 + ty * 4 + r) * S_LEN + n0 + tx * 4 + c] = acc[r][c] * 0.03125f;
}

// ---------------------------------------------------------------------------
// K3: row-wise softmax with exact f32-reference mask semantics.
//   i <  len[b]: softmax over j<=i of scores; zeros for j>i.
//   i >= len[b]: additive -1e9 over whole row collapses scores to exact ties
//                in fp32 -> uniform 1/(i+1) over j<=i.
// One block (256 thr) per row.
// ---------------------------------------------------------------------------
__global__ __launch_bounds__(256) void softmax_rows(
    float* __restrict__ P, const int* __restrict__ lengths)
{
    const int row = blockIdx.x;          // 0 .. B*S-1
    const int b = row >> 11;             // /2048
    const int i = row & (S_LEN - 1);
    float* p = P + (size_t)b * S_LEN * S_LEN + (size_t)i * S_LEN;
    const int len = lengths[b];
    const int t = threadIdx.x;
    const int nv = i + 1;                // valid j count (j <= i)

    if (i >= len) {
        const float u = 1.0f / (float)nv;
        for (int j = t; j < S_LEN; j += 256) p[j] = (j < nv) ? u : 0.0f;
        return;
    }

    float vals[8];
    float m = -INFINITY;
    #pragma unroll
    for (int r = 0; r < 8; ++r) {
        int j = t + r * 256;
        float xv = (j < nv) ? p[j] : -INFINITY;
        vals[r] = xv;
        m = fmaxf(m, xv);
    }

    __shared__ float red[256];
    red[t] = m; __syncthreads();
    #pragma unroll
    for (int s2 = 128; s2 > 0; s2 >>= 1) {
        if (t < s2) red[t] = fmaxf(red[t], red[t + s2]);
        __syncthreads();
    }
    const float M = red[0];
    __syncthreads();

    float s = 0.0f;
    #pragma unroll
    for (int r = 0; r < 8; ++r) {
        int j = t + r * 256;
        if (j < nv) { vals[r] = __expf(vals[r] - M); s += vals[r]; }
    }
    red[t] = s; __syncthreads();
    #pragma unroll
    for (int s2 = 128; s2 > 0; s2 >>= 1) {
        if (t < s2) red[t] += red[t + s2];
        __syncthreads();
    }
    const float inv = 1.0f / red[0];

    #pragma unroll
    for (int r = 0; r < 8; ++r) {
        int j = t + r * 256;
        if (j < S_LEN) p[j] = (j < nv) ? vals[r] * inv : 0.0f;
    }
}

// ---------------------------------------------------------------------------
// K4: O[b][i][o] = sum_j P[b][i][j] * v[b][j][o].
// A = P[b] (row-major, k=j contiguous), B = v[b] (row-major, n=o contiguous).
// K-loop capped at (bi+1)*64 (P is zero for j>i inside that range).
// grid(S/64, DK/64, B), block(16,16).
// ---------------------------------------------------------------------------
__global__ __launch_bounds__(256) void pv_gemm(
    const float* __restrict__ P, const float* __restrict__ v,
    float* __restrict__ out)
{
    const int bi = blockIdx.x, bn = blockIdx.y, b = blockIdx.z;
    const float* A  = P + (size_t)b * S_LEN * S_LEN;
    const float* Bm = v + (size_t)b * S_LEN * DK;

    __shared__ float As[16][68];
    __shared__ float Bs[16][68];
    const int tx = threadIdx.x, ty = threadIdx.y;
    const int tid = ty * 16 + tx;
    const int m0 = bi * 64, n0 = bn * 64;
    const int lrow = tid >> 2;         // 0..63 (A rows)
    const int lq   = (tid & 3) * 4;    // k offset for A
    const int krow = tid >> 4;         // 0..15 (B k row)
    const int cq   = (tid & 15) * 4;   // 0..60 (B col)

    const int kmax = m0 + 64;          // j <= i_max of this tile

    float acc[4][4] = {};

    for (int k0 = 0; k0 < kmax; k0 += 16) {
        float4 a4 = *(const float4*)&A [(size_t)(m0 + lrow) * S_LEN + k0 + lq];
        float4 b4 = *(const float4*)&Bm[(size_t)(k0 + krow) * DK + n0 + cq];
        As[lq+0][lrow] = a4.x; As[lq+1][lrow] = a4.y; As[lq+2][lrow] = a4.z; As[lq+3][lrow] = a4.w;
        *(float4*)&Bs[krow][cq] = b4;
        __syncthreads();
        #pragma unroll
        for (int kk = 0; kk < 16; ++kk) {
            float4 a = *(const float4*)&As[kk][ty * 4];
            float4 b = *(const float4*)&Bs[kk][tx * 4];
            float av[4] = {a.x, a.y, a.z, a.w};
            float bw[4] = {b.x, b.y, b.z, b.w};
            #pragma unroll
            for (int r = 0; r < 4; ++r)
                #pragma unroll
                for (int c = 0; c < 4; ++c)
                    acc[r][c] += av[r] * bw[c];
        }
        __syncthreads();
    }
    #pragma unroll
    for (int r = 0; r < 4; ++r)
        #pragma unroll
        for (int c = 0; c < 4; ++c)
            out[((size_t)b * S_LEN + m0 + ty * 4 + r) * DK + n0 + tx * 4 + c] = acc[r][c];
}

// ---------------------------------------------------------------------------
extern "C" void kernel_launch(void* const* d_in, const int* in_sizes, int n_in,
                              void* d_out, int out_size, void* d_ws, size_t ws_size,
                              hipStream_t stream)
{
    const float* x  = (const float*)d_in[0];
    const float* Wq = (const float*)d_in[1];
    const float* bq = (const float*)d_in[2];
    const float* Wk = (const float*)d_in[3];
    const float* bk = (const float*)d_in[4];
    const float* Wv = (const float*)d_in[5];
    const float* bv = (const float*)d_in[6];
    const int* lengths = (const int*)d_in[7];
    float* out = (float*)d_out;

    // workspace layout (fp32): q | k | v | P   = 167.8 MB total
    float* q = (float*)d_ws;
    float* k = q + (size_t)NB * S_LEN * DK;
    float* v = k + (size_t)NB * S_LEN * DK;
    float* P = v + (size_t)NB * S_LEN * DK;

    dim3 blk(16, 16);
    qkv_gemm<<<dim3(8192 / 64, DK / 64, 3), blk, 0, stream>>>(
        x, Wq, bq, Wk, bk, Wv, bv, q, k, v);
    score_gemm<<<dim3(S_LEN / 64, S_LEN / 64, NB), blk, 0, stream>>>(q, k, P);
    softmax_rows<<<dim3(NB * S_LEN), dim3(256), 0, stream>>>(P, lengths);
    pv_gemm<<<dim3(S_LEN / 64, DK / 64, NB), blk, 0, stream>>>(P, v, out);
}

// Round 2
// 288.946 us; speedup vs baseline: 5.0646x; 5.0646x over previous
//
#include <hip/hip_runtime.h>
#include <cstddef>
#include <cstdint>

#define NB 4
#define S_LEN 2048
#define DK 1024

typedef __attribute__((ext_vector_type(8))) short short8;       // 8 bf16 = 4 VGPR (MFMA A/B frag)
typedef __attribute__((ext_vector_type(4))) float floatx4;      // MFMA C/D frag
typedef __attribute__((ext_vector_type(4))) unsigned short ushort4v;
typedef __attribute__((ext_vector_type(8))) unsigned short ushort8v;

__device__ inline unsigned short f2bf(float f) {
    unsigned int u = __float_as_uint(f);
    u += 0x7fff + ((u >> 16) & 1);   // round-to-nearest-even
    return (unsigned short)(u >> 16);
}

#define GLD16(gp, lp)                                                                  \
    __builtin_amdgcn_global_load_lds(                                                  \
        (const __attribute__((address_space(1))) unsigned int*)(gp),                   \
        (__attribute__((address_space(3))) unsigned int*)(lp), 16, 0, 0)

// ---------------------------------------------------------------------------
// K0: cast fp32 -> bf16 for x, Wq, Wk, Wv (one launch, z selects array)
// ---------------------------------------------------------------------------
__global__ __launch_bounds__(256) void cast_all(
    const float* __restrict__ x, const float* __restrict__ Wq,
    const float* __restrict__ Wk, const float* __restrict__ Wv,
    unsigned short* __restrict__ xb, unsigned short* __restrict__ wqb,
    unsigned short* __restrict__ wkb, unsigned short* __restrict__ wvb)
{
    const float* src; unsigned short* dst; int n4;
    if (blockIdx.z == 0)      { src = x;  dst = xb;  n4 = (int)((size_t)NB * S_LEN * DK / 4); }
    else if (blockIdx.z == 1) { src = Wq; dst = wqb; n4 = DK * DK / 4; }
    else if (blockIdx.z == 2) { src = Wk; dst = wkb; n4 = DK * DK / 4; }
    else                      { src = Wv; dst = wvb; n4 = DK * DK / 4; }
    const int stride = gridDim.x * 256;
    for (int i = blockIdx.x * 256 + threadIdx.x; i < n4; i += stride) {
        float4 f = ((const float4*)src)[i];
        ushort4v o;
        o.x = f2bf(f.x); o.y = f2bf(f.y); o.z = f2bf(f.z); o.w = f2bf(f.w);
        ((ushort4v*)dst)[i] = o;
    }
}

// ---------------------------------------------------------------------------
// K1: fused QKV projection, bf16 MFMA.  C[m][n] = sum_k X[m][k] W[n][k] + b[n]
// M=8192 N=1024 K=1024.  128x128 tile, BK=32, 4 waves x (4x4 of 16x16x32).
// z==2 (v) writes TRANSPOSED: vT[b][o][s]  (PV GEMM wants B k-major).
// ---------------------------------------------------------------------------
__global__ __launch_bounds__(256) void qkv_mfma(
    const unsigned short* __restrict__ xb,
    const unsigned short* __restrict__ wqb, const unsigned short* __restrict__ wkb,
    const unsigned short* __restrict__ wvb,
    const float* __restrict__ bq, const float* __restrict__ bk, const float* __restrict__ bv,
    unsigned short* __restrict__ qb, unsigned short* __restrict__ kb,
    unsigned short* __restrict__ vTb)
{
    __shared__ unsigned short As[128 * 32];
    __shared__ unsigned short Bs[128 * 32];
    const int tid  = threadIdx.x;
    const int w    = tid >> 6, lane = tid & 63;
    const int lm   = lane & 15, quad = lane >> 4;
    const int m0   = blockIdx.x * 128, n0 = blockIdx.y * 128;
    const int z    = blockIdx.z;
    const unsigned short* Wb = (z == 0) ? wqb : (z == 1) ? wkb : wvb;
    const float* bias        = (z == 0) ? bq  : (z == 1) ? bk  : bv;

    const int srow = w * 32 + (lane >> 2);   // staging row within 128-tile
    const int scol = (lane & 3) * 8;         // staging k-offset (elements)
    const unsigned short* Ag = xb + (size_t)(m0 + srow) * DK + scol;
    const unsigned short* Bg = Wb + (size_t)(n0 + srow) * DK + scol;
    unsigned short* Al = &As[w * 1024];
    unsigned short* Bl = &Bs[w * 1024];

    const int wr = (w >> 1) * 64, wc = (w & 1) * 64;

    floatx4 acc[4][4];
    #pragma unroll
    for (int r = 0; r < 4; ++r)
        #pragma unroll
        for (int c = 0; c < 4; ++c) acc[r][c] = (floatx4)0.0f;

    for (int k0 = 0; k0 < DK; k0 += 32) {
        GLD16(Ag + k0,                 Al);
        GLD16(Ag + k0 + (size_t)16*DK, Al + 512);
        GLD16(Bg + k0,                 Bl);
        GLD16(Bg + k0 + (size_t)16*DK, Bl + 512);
        __syncthreads();
        short8 af[4], bf[4];
        #pragma unroll
        for (int r = 0; r < 4; ++r) af[r] = *(const short8*)&As[(wr + r*16 + lm) * 32 + quad * 8];
        #pragma unroll
        for (int c = 0; c < 4; ++c) bf[c] = *(const short8*)&Bs[(wc + c*16 + lm) * 32 + quad * 8];
        #pragma unroll
        for (int r = 0; r < 4; ++r)
            #pragma unroll
            for (int c = 0; c < 4; ++c)
                acc[r][c] = __builtin_amdgcn_mfma_f32_16x16x32_bf16(af[r], bf[c], acc[r][c], 0, 0, 0);
        __syncthreads();
    }

    if (z < 2) {
        unsigned short* out = (z == 0) ? qb : kb;
        #pragma unroll
        for (int r = 0; r < 4; ++r) {
            const int gm = m0 + wr + r * 16 + quad * 4;
            #pragma unroll
            for (int c = 0; c < 4; ++c) {
                const int gn = n0 + wc + c * 16 + lm;
                const float bb = bias[gn];
                #pragma unroll
                for (int e = 0; e < 4; ++e)
                    out[(size_t)(gm + e) * DK + gn] = f2bf(acc[r][c][e] + bb);
            }
        }
    } else {
        const int bidx = m0 >> 11;              // 128-tile never crosses a batch
        #pragma unroll
        for (int r = 0; r < 4; ++r) {
            const int gm = m0 + wr + r * 16 + quad * 4;
            const int sm = gm & (S_LEN - 1);
            #pragma unroll
            for (int c = 0; c < 4; ++c) {
                const int gn = n0 + wc + c * 16 + lm;
                const float bb = bias[gn];
                ushort4v pk;
                pk.x = f2bf(acc[r][c][0] + bb);
                pk.y = f2bf(acc[r][c][1] + bb);
                pk.z = f2bf(acc[r][c][2] + bb);
                pk.w = f2bf(acc[r][c][3] + bb);
                *(ushort4v*)&vTb[((size_t)bidx * DK + gn) * S_LEN + sm] = pk;
            }
        }
    }
}

// ---------------------------------------------------------------------------
// K2: scores bf16 MFMA.  Pf[b][i][j] = (q[b,i,:]·k[b,j,:]) / 32  (fp32 out).
// Tiles with bj > bi skipped (causal).  Diagonal-tile j>i garbage is ignored
// by the softmax.
// ---------------------------------------------------------------------------
__global__ __launch_bounds__(256) void score_mfma(
    const unsigned short* __restrict__ qb, const unsigned short* __restrict__ kb,
    float* __restrict__ Pf)
{
    const int bi = blockIdx.x, bj = blockIdx.y, b = blockIdx.z;
    if (bj > bi) return;

    __shared__ unsigned short As[128 * 32];
    __shared__ unsigned short Bs[128 * 32];
    const int tid  = threadIdx.x;
    const int w    = tid >> 6, lane = tid & 63;
    const int lm   = lane & 15, quad = lane >> 4;
    const int m0   = bi * 128, n0 = bj * 128;
    const unsigned short* Aq = qb + (size_t)b * S_LEN * DK;
    const unsigned short* Bk = kb + (size_t)b * S_LEN * DK;
    float* Pb_ = Pf + (size_t)b * S_LEN * S_LEN;

    const int srow = w * 32 + (lane >> 2);
    const int scol = (lane & 3) * 8;
    const unsigned short* Ag = Aq + (size_t)(m0 + srow) * DK + scol;
    const unsigned short* Bg = Bk + (size_t)(n0 + srow) * DK + scol;
    unsigned short* Al = &As[w * 1024];
    unsigned short* Bl = &Bs[w * 1024];

    const int wr = (w >> 1) * 64, wc = (w & 1) * 64;

    floatx4 acc[4][4];
    #pragma unroll
    for (int r = 0; r < 4; ++r)
        #pragma unroll
        for (int c = 0; c < 4; ++c) acc[r][c] = (floatx4)0.0f;

    for (int k0 = 0; k0 < DK; k0 += 32) {
        GLD16(Ag + k0,                 Al);
        GLD16(Ag + k0 + (size_t)16*DK, Al + 512);
        GLD16(Bg + k0,                 Bl);
        GLD16(Bg + k0 + (size_t)16*DK, Bl + 512);
        __syncthreads();
        short8 af[4], bf[4];
        #pragma unroll
        for (int r = 0; r < 4; ++r) af[r] = *(const short8*)&As[(wr + r*16 + lm) * 32 + quad * 8];
        #pragma unroll
        for (int c = 0; c < 4; ++c) bf[c] = *(const short8*)&Bs[(wc + c*16 + lm) * 32 + quad * 8];
        #pragma unroll
        for (int r = 0; r < 4; ++r)
            #pragma unroll
            for (int c = 0; c < 4; ++c)
                acc[r][c] = __builtin_amdgcn_mfma_f32_16x16x32_bf16(af[r], bf[c], acc[r][c], 0, 0, 0);
        __syncthreads();
    }

    #pragma unroll
    for (int r = 0; r < 4; ++r) {
        const int gm = m0 + wr + r * 16 + quad * 4;
        #pragma unroll
        for (int c = 0; c < 4; ++c) {
            const int gn = n0 + wc + c * 16 + lm;
            #pragma unroll
            for (int e = 0; e < 4; ++e)
                Pb_[(size_t)(gm + e) * S_LEN + gn] = acc[r][c][e] * 0.03125f;
        }
    }
}

// ---------------------------------------------------------------------------
// K3: softmax.  fp32 scores in, bf16 probabilities out (zeros for j>i).
//   i <  len[b]: causal softmax over j<=i
//   i >= len[b]: uniform 1/(i+1) over j<=i  (exact-tie fp32 semantics)
// ---------------------------------------------------------------------------
__global__ __launch_bounds__(256) void softmax_rows(
    const float* __restrict__ Pf, unsigned short* __restrict__ Pb,
    const int* __restrict__ lengths)
{
    const int row = blockIdx.x;              // 0 .. B*S-1
    const int b = row >> 11, i = row & (S_LEN - 1);
    const float* p = Pf + (size_t)row * S_LEN;
    unsigned short* o = Pb + (size_t)row * S_LEN;
    const int len = lengths[b];
    const int t = threadIdx.x;
    const int nv = i + 1;
    const int j0 = t * 8;

    if (i >= len) {
        const unsigned short u = f2bf(1.0f / (float)nv);
        ushort8v pk;
        #pragma unroll
        for (int e = 0; e < 8; ++e) pk[e] = (j0 + e < nv) ? u : (unsigned short)0;
        *(ushort8v*)&o[j0] = pk;
        return;
    }

    float v[8];
    float4 f0 = *(const float4*)&p[j0];
    float4 f1 = *(const float4*)&p[j0 + 4];
    v[0] = f0.x; v[1] = f0.y; v[2] = f0.z; v[3] = f0.w;
    v[4] = f1.x; v[5] = f1.y; v[6] = f1.z; v[7] = f1.w;

    float m = -INFINITY;
    #pragma unroll
    for (int e = 0; e < 8; ++e) {
        float xv = (j0 + e < nv) ? v[e] : -INFINITY;
        v[e] = xv;
        m = fmaxf(m, xv);
    }

    __shared__ float red[256];
    red[t] = m; __syncthreads();
    #pragma unroll
    for (int s2 = 128; s2 > 0; s2 >>= 1) {
        if (t < s2) red[t] = fmaxf(red[t], red[t + s2]);
        __syncthreads();
    }
    const float M = red[0];
    __syncthreads();

    float s = 0.0f;
    #pragma unroll
    for (int e = 0; e < 8; ++e) {
        if (j0 + e < nv) { v[e] = __expf(v[e] - M); s += v[e]; }
        else v[e] = 0.0f;
    }
    red[t] = s; __syncthreads();
    #pragma unroll
    for (int s2 = 128; s2 > 0; s2 >>= 1) {
        if (t < s2) red[t] += red[t + s2];
        __syncthreads();
    }
    const float inv = 1.0f / red[0];

    ushort8v pk;
    #pragma unroll
    for (int e = 0; e < 8; ++e) pk[e] = f2bf(v[e] * inv);
    *(ushort8v*)&o[j0] = pk;
}

// ---------------------------------------------------------------------------
// K4: O[b][i][o] = sum_j P[b][i][j] vT[b][o][j], bf16 MFMA, fp32 out.
// K-loop capped at (bi+1)*128 (P zero for j>i inside range).
// ---------------------------------------------------------------------------
__global__ __launch_bounds__(256) void pv_mfma(
    const unsigned short* __restrict__ Pb, const unsigned short* __restrict__ vTb,
    float* __restrict__ out)
{
    __shared__ unsigned short As[128 * 32];
    __shared__ unsigned short Bs[128 * 32];
    const int tid  = threadIdx.x;
    const int w    = tid >> 6, lane = tid & 63;
    const int lm   = lane & 15, quad = lane >> 4;
    const int bi = blockIdx.x, bn = blockIdx.y, b = blockIdx.z;
    const int m0 = bi * 128, n0 = bn * 128;
    const unsigned short* Ap = Pb  + (size_t)b * S_LEN * S_LEN;
    const unsigned short* Bv = vTb + (size_t)b * DK * S_LEN;

    const int srow = w * 32 + (lane >> 2);
    const int scol = (lane & 3) * 8;
    const unsigned short* Ag = Ap + (size_t)(m0 + srow) * S_LEN + scol;
    const unsigned short* Bg = Bv + (size_t)(n0 + srow) * S_LEN + scol;
    unsigned short* Al = &As[w * 1024];
    unsigned short* Bl = &Bs[w * 1024];

    const int wr = (w >> 1) * 64, wc = (w & 1) * 64;
    const int kend = (bi + 1) * 128;

    floatx4 acc[4][4];
    #pragma unroll
    for (int r = 0; r < 4; ++r)
        #pragma unroll
        for (int c = 0; c < 4; ++c) acc[r][c] = (floatx4)0.0f;

    for (int k0 = 0; k0 < kend; k0 += 32) {
        GLD16(Ag + k0,                    Al);
        GLD16(Ag + k0 + (size_t)16*S_LEN, Al + 512);
        GLD16(Bg + k0,                    Bl);
        GLD16(Bg + k0 + (size_t)16*S_LEN, Bl + 512);
        __syncthreads();
        short8 af[4], bf[4];
        #pragma unroll
        for (int r = 0; r < 4; ++r) af[r] = *(const short8*)&As[(wr + r*16 + lm) * 32 + quad * 8];
        #pragma unroll
        for (int c = 0; c < 4; ++c) bf[c] = *(const short8*)&Bs[(wc + c*16 + lm) * 32 + quad * 8];
        #pragma unroll
        for (int r = 0; r < 4; ++r)
            #pragma unroll
            for (int c = 0; c < 4; ++c)
                acc[r][c] = __builtin_amdgcn_mfma_f32_16x16x32_bf16(af[r], bf[c], acc[r][c], 0, 0, 0);
        __syncthreads();
    }

    #pragma unroll
    for (int r = 0; r < 4; ++r) {
        const int gm = m0 + wr + r * 16 + quad * 4;
        #pragma unroll
        for (int c = 0; c < 4; ++c) {
            const int gn = n0 + wc + c * 16 + lm;
            #pragma unroll
            for (int e = 0; e < 4; ++e)
                out[((size_t)b * S_LEN + gm + e) * DK + gn] = acc[r][c][e];
        }
    }
}

// ---------------------------------------------------------------------------
extern "C" void kernel_launch(void* const* d_in, const int* in_sizes, int n_in,
                              void* d_out, int out_size, void* d_ws, size_t ws_size,
                              hipStream_t stream)
{
    const float* x  = (const float*)d_in[0];
    const float* Wq = (const float*)d_in[1];
    const float* bq = (const float*)d_in[2];
    const float* Wk = (const float*)d_in[3];
    const float* bk = (const float*)d_in[4];
    const float* Wv = (const float*)d_in[5];
    const float* bv = (const float*)d_in[6];
    const int* lengths = (const int*)d_in[7];
    float* out = (float*)d_out;

    // workspace (shorts): qb | kb | vTb | xb | Wqb | Wkb | Wvb | Pf(fp32)
    // Pb (bf16 probs) aliases qb+kb (dead after score_mfma).  140.5 MB total.
    const size_t NQ = (size_t)NB * S_LEN * DK;       // 8388608
    const size_t NW = (size_t)DK * DK;               // 1048576
    unsigned short* ws16 = (unsigned short*)d_ws;
    unsigned short* qb  = ws16;
    unsigned short* kb_ = ws16 + NQ;
    unsigned short* vTb = ws16 + 2 * NQ;
    unsigned short* xb  = ws16 + 3 * NQ;
    unsigned short* wqb = ws16 + 4 * NQ;
    unsigned short* wkb = wqb + NW;
    unsigned short* wvb = wkb + NW;
    unsigned short* Pb  = ws16;                      // alias over qb+kb
    float* Pf = (float*)(ws16 + 4 * NQ + 3 * NW);

    cast_all<<<dim3(1024, 1, 4), 256, 0, stream>>>(x, Wq, Wk, Wv, xb, wqb, wkb, wvb);
    qkv_mfma<<<dim3(64, 8, 3), 256, 0, stream>>>(xb, wqb, wkb, wvb, bq, bk, bv, qb, kb_, vTb);
    score_mfma<<<dim3(16, 16, NB), 256, 0, stream>>>(qb, kb_, Pf);
    softmax_rows<<<dim3(NB * S_LEN), 256, 0, stream>>>(Pf, Pb, lengths);
    pv_mfma<<<dim3(16, 8, NB), 256, 0, stream>>>(Pb, vTb, out);
}

// Round 4
// 250.875 us; speedup vs baseline: 5.8331x; 1.1518x over previous
//
#include <hip/hip_runtime.h>
#include <cstddef>
#include <cstdint>

#define NB 4
#define S_LEN 2048
#define DK 1024

typedef __attribute__((ext_vector_type(8))) short short8;       // 8 bf16 = 4 VGPR (MFMA A/B frag)
typedef __attribute__((ext_vector_type(4))) float floatx4;      // MFMA C/D frag
typedef __attribute__((ext_vector_type(4))) unsigned short ushort4v;
typedef __attribute__((ext_vector_type(8))) unsigned short ushort8v;

__device__ inline unsigned short f2bf(float f) {
    unsigned int u = __float_as_uint(f);
    u += 0x7fff + ((u >> 16) & 1);   // round-to-nearest-even
    return (unsigned short)(u >> 16);
}
__device__ inline float bf2f(unsigned short u) {
    return __uint_as_float(((unsigned int)u) << 16);
}

#define GLD16(gp, lp)                                                                  \
    __builtin_amdgcn_global_load_lds(                                                  \
        (const __attribute__((address_space(1))) unsigned int*)(gp),                   \
        (__attribute__((address_space(3))) unsigned int*)(lp), 16, 0, 0)

// Stage a 128x64 bf16 tile into LDS with XOR swizzle: LDS[row][pg] holds
// global colgroup (pg ^ (row&7)) (colgroups of 8 el).  Fragment reads use
// pg = cg ^ (row&7), spreading the 16 m-lanes across 8 bank groups.
__device__ inline void stage128x64(const unsigned short* __restrict__ g, size_t ld,
                                   unsigned short* __restrict__ lds,
                                   int w, int lane)
{
    const int r8 = lane >> 3;                  // 0..7
    const int cg = (lane & 7) ^ r8;            // swizzled source colgroup
    const unsigned short* gp = g + (size_t)(w * 8 + r8) * ld + cg * 8;
    unsigned short* lp = lds + (size_t)(w * 8) * 64;
    #pragma unroll
    for (int seg = 0; seg < 4; ++seg)
        GLD16(gp + (size_t)(seg * 32) * ld, lp + (size_t)seg * 32 * 64);
}

// ---------------------------------------------------------------------------
// K0: cast fp32 -> bf16 for x, Wq, Wk, Wv
// ---------------------------------------------------------------------------
__global__ __launch_bounds__(256) void cast_all(
    const float* __restrict__ x, const float* __restrict__ Wq,
    const float* __restrict__ Wk, const float* __restrict__ Wv,
    unsigned short* __restrict__ xb, unsigned short* __restrict__ wqb,
    unsigned short* __restrict__ wkb, unsigned short* __restrict__ wvb)
{
    const float* src; unsigned short* dst; int n4;
    if (blockIdx.z == 0)      { src = x;  dst = xb;  n4 = (int)((size_t)NB * S_LEN * DK / 4); }
    else if (blockIdx.z == 1) { src = Wq; dst = wqb; n4 = DK * DK / 4; }
    else if (blockIdx.z == 2) { src = Wk; dst = wkb; n4 = DK * DK / 4; }
    else                      { src = Wv; dst = wvb; n4 = DK * DK / 4; }
    const int stride = gridDim.x * 256;
    for (int i = blockIdx.x * 256 + threadIdx.x; i < n4; i += stride) {
        float4 f = ((const float4*)src)[i];
        ushort4v o;
        o.x = f2bf(f.x); o.y = f2bf(f.y); o.z = f2bf(f.z); o.w = f2bf(f.w);
        ((ushort4v*)dst)[i] = o;
    }
}

// ---------------------------------------------------------------------------
// K1: fused QKV projection, bf16 MFMA, 128x128 tile, BK=64, swizzled LDS.
// z==2 (v) writes TRANSPOSED vT[b][o][s].
// ---------------------------------------------------------------------------
__global__ __launch_bounds__(256) void qkv_mfma(
    const unsigned short* __restrict__ xb,
    const unsigned short* __restrict__ wqb, const unsigned short* __restrict__ wkb,
    const unsigned short* __restrict__ wvb,
    const float* __restrict__ bq, const float* __restrict__ bk, const float* __restrict__ bv,
    unsigned short* __restrict__ qb, unsigned short* __restrict__ kb,
    unsigned short* __restrict__ vTb)
{
    __shared__ unsigned short As[128 * 64];
    __shared__ unsigned short Bs[128 * 64];
    const int tid  = threadIdx.x;
    const int w    = tid >> 6, lane = tid & 63;
    const int lm   = lane & 15, quad = lane >> 4;
    const int xr   = lm & 7;                   // row&7 of every fragment row this lane reads
    const int m0   = blockIdx.x * 128, n0 = blockIdx.y * 128;
    const int z    = blockIdx.z;
    const unsigned short* Wb = (z == 0) ? wqb : (z == 1) ? wkb : wvb;
    const float* bias        = (z == 0) ? bq  : (z == 1) ? bk  : bv;

    const unsigned short* Ag = xb + (size_t)m0 * DK;
    const unsigned short* Bg = Wb + (size_t)n0 * DK;

    const int wr = (w >> 1) * 64, wc = (w & 1) * 64;

    floatx4 acc[4][4];
    #pragma unroll
    for (int r = 0; r < 4; ++r)
        #pragma unroll
        for (int c = 0; c < 4; ++c) acc[r][c] = (floatx4)0.0f;

    for (int k0 = 0; k0 < DK; k0 += 64) {
        stage128x64(Ag + k0, DK, As, w, lane);
        stage128x64(Bg + k0, DK, Bs, w, lane);
        __syncthreads();
        #pragma unroll
        for (int ks = 0; ks < 2; ++ks) {
            short8 af[4], bf[4];
            #pragma unroll
            for (int r = 0; r < 4; ++r)
                af[r] = *(const short8*)&As[(size_t)(wr + r*16 + lm) * 64 + ((((ks<<2)|quad) ^ xr) << 3)];
            #pragma unroll
            for (int c = 0; c < 4; ++c)
                bf[c] = *(const short8*)&Bs[(size_t)(wc + c*16 + lm) * 64 + ((((ks<<2)|quad) ^ xr) << 3)];
            #pragma unroll
            for (int r = 0; r < 4; ++r)
                #pragma unroll
                for (int c = 0; c < 4; ++c)
                    acc[r][c] = __builtin_amdgcn_mfma_f32_16x16x32_bf16(af[r], bf[c], acc[r][c], 0, 0, 0);
        }
        __syncthreads();
    }

    if (z < 2) {
        unsigned short* out = (z == 0) ? qb : kb;
        #pragma unroll
        for (int r = 0; r < 4; ++r) {
            const int gm = m0 + wr + r * 16 + quad * 4;
            #pragma unroll
            for (int c = 0; c < 4; ++c) {
                const int gn = n0 + wc + c * 16 + lm;
                const float bb = bias[gn];
                #pragma unroll
                for (int e = 0; e < 4; ++e)
                    out[(size_t)(gm + e) * DK + gn] = f2bf(acc[r][c][e] + bb);
            }
        }
    } else {
        const int bidx = m0 >> 11;              // 128-tile never crosses a batch
        #pragma unroll
        for (int r = 0; r < 4; ++r) {
            const int gm = m0 + wr + r * 16 + quad * 4;
            const int sm = gm & (S_LEN - 1);
            #pragma unroll
            for (int c = 0; c < 4; ++c) {
                const int gn = n0 + wc + c * 16 + lm;
                const float bb = bias[gn];
                ushort4v pk;
                pk.x = f2bf(acc[r][c][0] + bb);
                pk.y = f2bf(acc[r][c][1] + bb);
                pk.z = f2bf(acc[r][c][2] + bb);
                pk.w = f2bf(acc[r][c][3] + bb);
                *(ushort4v*)&vTb[((size_t)bidx * DK + gn) * S_LEN + sm] = pk;
            }
        }
    }
}

// ---------------------------------------------------------------------------
// K2: scores, bf16 out.  Skips tiles above the diagonal only (geometry-based,
// length-independent coverage — every tile softmax can read is written).
// ---------------------------------------------------------------------------
__global__ __launch_bounds__(256) void score_mfma(
    const unsigned short* __restrict__ qb, const unsigned short* __restrict__ kb,
    unsigned short* __restrict__ Pf)
{
    const int bi = blockIdx.x, bj = blockIdx.y, b = blockIdx.z;
    if (bj > bi) return;
    const int m0 = bi * 128, n0 = bj * 128;

    __shared__ unsigned short As[128 * 64];
    __shared__ unsigned short Bs[128 * 64];
    const int tid  = threadIdx.x;
    const int w    = tid >> 6, lane = tid & 63;
    const int lm   = lane & 15, quad = lane >> 4;
    const int xr   = lm & 7;
    const unsigned short* Ag = qb + (size_t)b * S_LEN * DK + (size_t)m0 * DK;
    const unsigned short* Bg = kb + (size_t)b * S_LEN * DK + (size_t)n0 * DK;
    unsigned short* Pb_ = Pf + (size_t)b * S_LEN * S_LEN;

    const int wr = (w >> 1) * 64, wc = (w & 1) * 64;

    floatx4 acc[4][4];
    #pragma unroll
    for (int r = 0; r < 4; ++r)
        #pragma unroll
        for (int c = 0; c < 4; ++c) acc[r][c] = (floatx4)0.0f;

    for (int k0 = 0; k0 < DK; k0 += 64) {
        stage128x64(Ag + k0, DK, As, w, lane);
        stage128x64(Bg + k0, DK, Bs, w, lane);
        __syncthreads();
        #pragma unroll
        for (int ks = 0; ks < 2; ++ks) {
            short8 af[4], bf[4];
            #pragma unroll
            for (int r = 0; r < 4; ++r)
                af[r] = *(const short8*)&As[(size_t)(wr + r*16 + lm) * 64 + ((((ks<<2)|quad) ^ xr) << 3)];
            #pragma unroll
            for (int c = 0; c < 4; ++c)
                bf[c] = *(const short8*)&Bs[(size_t)(wc + c*16 + lm) * 64 + ((((ks<<2)|quad) ^ xr) << 3)];
            #pragma unroll
            for (int r = 0; r < 4; ++r)
                #pragma unroll
                for (int c = 0; c < 4; ++c)
                    acc[r][c] = __builtin_amdgcn_mfma_f32_16x16x32_bf16(af[r], bf[c], acc[r][c], 0, 0, 0);
        }
        __syncthreads();
    }

    #pragma unroll
    for (int r = 0; r < 4; ++r) {
        const int gm = m0 + wr + r * 16 + quad * 4;
        #pragma unroll
        for (int c = 0; c < 4; ++c) {
            const int gn = n0 + wc + c * 16 + lm;
            #pragma unroll
            for (int e = 0; e < 4; ++e)
                Pb_[(size_t)(gm + e) * S_LEN + gn] = f2bf(acc[r][c][e] * 0.03125f);
        }
    }
}

// ---------------------------------------------------------------------------
// K3: softmax.  bf16 scores in, bf16 probabilities out.  Writes the FULL
// 2048-wide row every launch (zeros beyond nv) — output coverage is
// length-independent.
//   i <  len[b]: causal softmax over j<=i
//   i >= len[b]: uniform 1/(i+1) over j<=i  (exact-tie fp32 semantics)
// ---------------------------------------------------------------------------
__global__ __launch_bounds__(256) void softmax_rows(
    const unsigned short* __restrict__ Pf, unsigned short* __restrict__ Pb,
    const int* __restrict__ lengths)
{
    const int row = blockIdx.x;              // 0 .. B*S-1
    const int b = row >> 11, i = row & (S_LEN - 1);
    const unsigned short* p = Pf + (size_t)row * S_LEN;
    unsigned short* o = Pb + (size_t)row * S_LEN;
    const int len = lengths[b];
    const int t = threadIdx.x;
    const int nv = i + 1;
    const int j0 = t * 8;

    if (i >= len) {
        const unsigned short u = f2bf(1.0f / (float)nv);
        ushort8v pk;
        #pragma unroll
        for (int e = 0; e < 8; ++e) pk[e] = (j0 + e < nv) ? u : (unsigned short)0;
        *(ushort8v*)&o[j0] = pk;
        return;
    }

    float v[8];
    float m = -INFINITY;
    if (j0 < nv) {
        ushort8v raw = *(const ushort8v*)&p[j0];
        #pragma unroll
        for (int e = 0; e < 8; ++e) {
            float xv = (j0 + e < nv) ? bf2f(raw[e]) : -INFINITY;
            v[e] = xv;
            m = fmaxf(m, xv);
        }
    } else {
        #pragma unroll
        for (int e = 0; e < 8; ++e) v[e] = -INFINITY;
    }

    __shared__ float red[256];
    red[t] = m; __syncthreads();
    #pragma unroll
    for (int s2 = 128; s2 > 0; s2 >>= 1) {
        if (t < s2) red[t] = fmaxf(red[t], red[t + s2]);
        __syncthreads();
    }
    const float M = red[0];
    __syncthreads();

    float s = 0.0f;
    #pragma unroll
    for (int e = 0; e < 8; ++e) {
        if (j0 + e < nv) { v[e] = __expf(v[e] - M); s += v[e]; }
        else v[e] = 0.0f;
    }
    red[t] = s; __syncthreads();
    #pragma unroll
    for (int s2 = 128; s2 > 0; s2 >>= 1) {
        if (t < s2) red[t] += red[t + s2];
        __syncthreads();
    }
    const float inv = 1.0f / red[0];

    ushort8v pk;
    #pragma unroll
    for (int e = 0; e < 8; ++e) pk[e] = f2bf(v[e] * inv);   // v[e]==0 beyond nv
    *(ushort8v*)&o[j0] = pk;
}

// ---------------------------------------------------------------------------
// K4: O[b][i][o] = sum_j P[b][i][j] vT[b][o][j], bf16 MFMA, fp32 out.
// K-loop capped at (bi+1)*128 (P zero for j>i; rows fully written).
// ---------------------------------------------------------------------------
__global__ __launch_bounds__(256) void pv_mfma(
    const unsigned short* __restrict__ Pb, const unsigned short* __restrict__ vTb,
    float* __restrict__ out)
{
    __shared__ unsigned short As[128 * 64];
    __shared__ unsigned short Bs[128 * 64];
    const int tid  = threadIdx.x;
    const int w    = tid >> 6, lane = tid & 63;
    const int lm   = lane & 15, quad = lane >> 4;
    const int xr   = lm & 7;
    const int bi = blockIdx.x, bn = blockIdx.y, b = blockIdx.z;
    const int m0 = bi * 128, n0 = bn * 128;
    const unsigned short* Ag = Pb  + (size_t)b * S_LEN * S_LEN + (size_t)m0 * S_LEN;
    const unsigned short* Bg = vTb + (size_t)b * DK * S_LEN    + (size_t)n0 * S_LEN;

    const int wr = (w >> 1) * 64, wc = (w & 1) * 64;
    const int kend = (bi + 1) * 128;

    floatx4 acc[4][4];
    #pragma unroll
    for (int r = 0; r < 4; ++r)
        #pragma unroll
        for (int c = 0; c < 4; ++c) acc[r][c] = (floatx4)0.0f;

    for (int k0 = 0; k0 < kend; k0 += 64) {
        stage128x64(Ag + k0, S_LEN, As, w, lane);
        stage128x64(Bg + k0, S_LEN, Bs, w, lane);
        __syncthreads();
        #pragma unroll
        for (int ks = 0; ks < 2; ++ks) {
            short8 af[4], bf[4];
            #pragma unroll
            for (int r = 0; r < 4; ++r)
                af[r] = *(const short8*)&As[(size_t)(wr + r*16 + lm) * 64 + ((((ks<<2)|quad) ^ xr) << 3)];
            #pragma unroll
            for (int c = 0; c < 4; ++c)
                bf[c] = *(const short8*)&Bs[(size_t)(wc + c*16 + lm) * 64 + ((((ks<<2)|quad) ^ xr) << 3)];
            #pragma unroll
            for (int r = 0; r < 4; ++r)
                #pragma unroll
                for (int c = 0; c < 4; ++c)
                    acc[r][c] = __builtin_amdgcn_mfma_f32_16x16x32_bf16(af[r], bf[c], acc[r][c], 0, 0, 0);
        }
        __syncthreads();
    }

    #pragma unroll
    for (int r = 0; r < 4; ++r) {
        const int gm = m0 + wr + r * 16 + quad * 4;
        #pragma unroll
        for (int c = 0; c < 4; ++c) {
            const int gn = n0 + wc + c * 16 + lm;
            #pragma unroll
            for (int e = 0; e < 4; ++e)
                out[((size_t)b * S_LEN + gm + e) * DK + gn] = acc[r][c][e];
        }
    }
}

// ---------------------------------------------------------------------------
extern "C" void kernel_launch(void* const* d_in, const int* in_sizes, int n_in,
                              void* d_out, int out_size, void* d_ws, size_t ws_size,
                              hipStream_t stream)
{
    const float* x  = (const float*)d_in[0];
    const float* Wq = (const float*)d_in[1];
    const float* bq = (const float*)d_in[2];
    const float* Wk = (const float*)d_in[3];
    const float* bk = (const float*)d_in[4];
    const float* Wv = (const float*)d_in[5];
    const float* bv = (const float*)d_in[6];
    const int* lengths = (const int*)d_in[7];
    float* out = (float*)d_out;

    // workspace (bf16 elements): qb | kb | vTb | xb | Wqb | Wkb | Wvb | Pf16
    // Pb (probs) aliases qb+kb (dead after score_mfma).  ~107 MB total.
    const size_t NQ = (size_t)NB * S_LEN * DK;       // 8388608
    const size_t NW = (size_t)DK * DK;               // 1048576
    unsigned short* ws16 = (unsigned short*)d_ws;
    unsigned short* qb  = ws16;
    unsigned short* kb_ = ws16 + NQ;
    unsigned short* vTb = ws16 + 2 * NQ;
    unsigned short* xb  = ws16 + 3 * NQ;
    unsigned short* wqb = ws16 + 4 * NQ;
    unsigned short* wkb = wqb + NW;
    unsigned short* wvb = wkb + NW;
    unsigned short* Pf  = ws16 + 4 * NQ + 3 * NW;    // bf16 scores
    unsigned short* Pb  = ws16;                      // alias over qb+kb

    cast_all<<<dim3(1024, 1, 4), 256, 0, stream>>>(x, Wq, Wk, Wv, xb, wqb, wkb, wvb);
    qkv_mfma<<<dim3(64, 8, 3), 256, 0, stream>>>(xb, wqb, wkb, wvb, bq, bk, bv, qb, kb_, vTb);
    score_mfma<<<dim3(16, 16, NB), 256, 0, stream>>>(qb, kb_, Pf);
    softmax_rows<<<dim3(NB * S_LEN), 256, 0, stream>>>(Pf, Pb, lengths);
    pv_mfma<<<dim3(16, 8, NB), 256, 0, stream>>>(Pb, vTb, out);
}